// Round 3
// baseline (264.714 us; speedup 1.0000x reference)
//
#include <hip/hip_runtime.h>
#include <hip/hip_fp16.h>

// AudioStructuralAnalyzer fused kernel, round 5.
// vs round 4 (127 us dispatch, VALUBusy 47%, HBM 24% -> STALL-bound, not VALU):
//  - T14 async-stage split: x tile prefetched into 4 float2 regs; channel 1's
//    global loads issue right after channel 0's A-barrier and land ~9.5K cycles
//    before use. Phase A is now pure ds_writes (no exposed vmcnt stall).
//  - Phase C and D1 merged into one barrier slot (C: reads s_u / writes P2.y;
//    D1: reads P0 / writes tmp — independent buffers).
//  - loop-top barrier only for c==1 (nothing to protect on first iteration).
//  => 15 barriers/block instead of 18, A-latency fully hidden.
// All arithmetic bit-identical to round 4 (absmax should stay 0.0039).

#define F_DIM 256
#define T_DIM 2048
#define B_DIM 8
#define C_DIM 2
#define TILE  32

#define XROWS 40          // x tile: halo 4
#define XS    40          // even stride, no pad (float2 loads stay aligned)
#define UROWS 38          // (ux,uy): halo 3
#define US    40          // stored with +1 col shift: u(r,cc) at word r*US+cc+1
#define FROWS 36          // field tiles: halo 2
#define FS    36
#define FH2   18          // FS/2 uint2 pairs per row
#define EPSF  1e-10f
#define NLD   4           // XROWS*20 = 800 float2 loads / 256 threads -> 4 regs

template<bool V> struct BoolC { static constexpr bool value = V; };

static __device__ __forceinline__ __half2 pack_h2(float a, float b) {
    auto v = __builtin_amdgcn_cvt_pkrtz(a, b);   // v_cvt_pkrtz_f16_f32, 1 inst
    return *(__half2*)&v;
}
static __device__ __forceinline__ float clamp01(float x) {
    return fminf(fmaxf(x, 0.f), 1.f);
}

__global__ __launch_bounds__(256, 4)
void audio_struct_fused(const float* __restrict__ x_in,
                        const float* __restrict__ gk_in,
                        float* __restrict__ out)
{
    __shared__ __align__(16) float   s_x [XROWS*XS];    // 6400 B
    __shared__ __align__(16) __half2 s_u [UROWS*US];    // 6080 B (ux,uy), col-shifted
    __shared__ __align__(16) __half2 s_P0[FROWS*FS];    // 5184 B (trace,diff)
    __shared__ __align__(16) __half2 s_P1[FROWS*FS];    // 5184 B (sxy,tin) -> (ua,va)
    __shared__ __align__(16) __half2 s_P2[FROWS*FS];    // 5184 B (sf,cv)
    __shared__ __align__(16) float   s_tmp[TILE*FS];    // 4608 B ping-pong
    // total 32640 B -> 5 blocks/CU (160 KiB)

    const int tx  = threadIdx.x;          // 0..31 (time)
    const int ty  = threadIdx.y;          // 0..7  (freq)
    const int tid = ty * 32 + tx;
    const int t0  = blockIdx.x * TILE;
    const int f0  = blockIdx.y * TILE;
    const int b   = blockIdx.z;

    const bool interior = (f0 >= 4) && (f0 + TILE + 4 <= F_DIM) &&
                          (t0 >= 4) && (t0 + TILE + 4 <= T_DIM);

    // ---- register-staged tile load / store (T14 async split) ----
    auto ld_tile = [&](const float* xp, float2* pf) {
        if (interior) {
            #pragma unroll
            for (int k = 0; k < NLD; ++k) {
                int idx = tid + k * 256;
                if (idx < XROWS * 20) {           // k<3 always; k==3: tid<32
                    int r = idx / 20, c2 = idx - r * 20;
                    pf[k] = *(const float2*)(xp + (size_t)(f0 + r - 4) * T_DIM
                                                + (t0 + c2 * 2 - 4));
                }
            }
        } else {
            #pragma unroll
            for (int k = 0; k < NLD; ++k) {
                int idx = tid + k * 256;
                pf[k] = make_float2(0.f, 0.f);
                if (idx < XROWS * 20) {
                    int r = idx / 20, c2 = idx - r * 20;
                    int gf = f0 + r - 4, gt = t0 + c2 * 2 - 4;
                    if ((unsigned)gf < (unsigned)F_DIM && (unsigned)gt < (unsigned)T_DIM)
                        pf[k] = *(const float2*)(xp + (size_t)gf * T_DIM + gt);
                }
            }
        }
    };
    auto st_tile = [&](const float2* pf) {
        #pragma unroll
        for (int k = 0; k < NLD; ++k) {
            int idx = tid + k * 256;
            if (idx < XROWS * 20) {
                int r = idx / 20, c2 = idx - r * 20;
                *(float2*)&s_x[r * XS + c2 * 2] = pf[k];
            }
        }
    };

    // issue channel-0 loads before anything else (overlap with gk setup)
    const float* xp0 = x_in + (size_t)(b * C_DIM + 0) * F_DIM * T_DIM;
    const float* xp1 = x_in + (size_t)(b * C_DIM + 1) * F_DIM * T_DIM;
    float2 pf[NLD];
    ld_tile(xp0, pf);

    // 1D gaussian = normalized middle row of the separable 5x5 kernel
    float r0 = gk_in[10], r1 = gk_in[11], r2 = gk_in[12], r3 = gk_in[13], r4 = gk_in[14];
    float winv = __builtin_amdgcn_rcpf(r0 + r1 + r2 + r3 + r4);
    const float w[5] = {r0*winv, r1*winv, r2*winv, r3*winv, r4*winv};
    const __half2 wh2[5] = {pack_h2(w[0],w[0]), pack_h2(w[1],w[1]), pack_h2(w[2],w[2]),
                            pack_h2(w[3],w[3]), pack_h2(w[4],w[4])};
    const __half2 h2z    = pack_h2(0.f, 0.f);
    const __half2 two    = pack_h2(2.f, 2.f);
    const __half2 eighth = pack_h2(0.125f, 0.125f);

    // paired pk vertical pass: dst[idx] = sum_i w[i]*src[idx + i*FH2] (uint2 lanes)
    auto vpass_pair = [&](const __half2* src, __half2* dst) {
        const uint2* s = (const uint2*)src;
        uint2* d = (uint2*)dst;
        for (int idx = tid; idx < TILE * FH2; idx += 256) {
            __half2 a0 = h2z, a1 = h2z;
            #pragma unroll
            for (int i = 0; i < 5; ++i) {
                uint2 v = s[idx + i * FH2];
                a0 = __hfma2(wh2[i], *(const __half2*)&v.x, a0);
                a1 = __hfma2(wh2[i], *(const __half2*)&v.y, a1);
            }
            uint2 o; o.x = *(const unsigned*)&a0; o.y = *(const unsigned*)&a1;
            d[idx] = o;
        }
    };

    float acc[6][4];
    #pragma unroll
    for (int k = 0; k < 6; ++k)
        #pragma unroll
        for (int s = 0; s < 4; ++s) acc[k][s] = 0.0f;

    // ---- Phase B + (C merged with D1), templated on interior fast path ----
    auto phaseBCD1 = [&](auto FASTC) {
        constexpr bool FAST = decltype(FASTC)::value;

        // ---- Phase B: (ux,uy) on 38x38; packed fields on 36x36 ----
        for (int idx = tid; idx < UROWS * UROWS; idx += 256) {
            int r = idx / UROWS, cc = idx - r * UROWS;
            float ux = 0.f, uy = 0.f, trp = 0.f, dfp = 0.f, sxy = 0.f,
                  tin = 0.f, sf = 0.f;
            bool ok = true;
            if (!FAST) {
                int gfr = f0 + r - 3, gtc = t0 + cc - 3;
                ok = ((unsigned)gfr < (unsigned)F_DIM) & ((unsigned)gtc < (unsigned)T_DIM);
            }
            if (ok) {
                const float* xc = &s_x[(r + 1) * XS + (cc + 1)];
                float x00 = xc[-XS-1], x01 = xc[-XS], x02 = xc[-XS+1];
                float x10 = xc[-1],                   x12 = xc[1];
                float x20 = xc[XS-1],  x21 = xc[XS],  x22 = xc[XS+1];
                // cross-correlation (XLA conv does not flip kernels)
                float gfv = ((x20 + 2.f*x21 + x22) - (x00 + 2.f*x01 + x02)) * 0.125f;
                float gtv = ((x02 + 2.f*x12 + x22) - (x00 + 2.f*x10 + x20)) * 0.125f;
                float gte = gtv + EPSF;
                float g2f = gfv * gfv;
                float d2  = fmaf(gte, gte, g2f);
                float rh  = __builtin_amdgcn_rsqf(d2);
                ux = gte * rh;                  // cos(atan2(gf, gt+eps))
                uy = gfv * rh;                  // sin(atan2(gf, gt+eps))
                // m2 = |grad|^2 + eps = mag^2;  vx=mag*ux, vy=mag*uy =>
                // trp = vx^2+vy^2 = m2,  dfp = vx^2-vy^2 = m2(ux-uy)(ux+uy),
                // sxy = vx*vy = m2*ux*uy  (identical algebra, no sqrt needed)
                float m2 = fmaf(gtv, gtv, g2f) + EPSF;
                trp = m2;
                dfp = m2 * (ux - uy) * (ux + uy);
                sxy = m2 * ux * uy;
                tin = __builtin_amdgcn_rcpf(1.0f + fabsf(gtv));
                sf  = fabsf(gfv);
            }
            s_u[r * US + cc + 1] = pack_h2(ux, uy);   // +1 col shift
            if (r >= 1 && r < UROWS - 1 && cc >= 1 && cc < UROWS - 1) {
                int fi = (r - 1) * FS + (cc - 1);
                s_P0[fi] = pack_h2(trp, dfp);
                s_P1[fi] = pack_h2(sxy, tin);
                s_P2[fi] = pack_h2(sf, 0.f);   // .y = cv, filled in Phase C
            }
        }
        __syncthreads();

        // ---- Phase C: curv on 36x36, packed-h2 sobel over (ux,uy) ----
        for (int idx = tid; idx < FROWS * FROWS; idx += 256) {
            int r = idx / FROWS, cc = idx - r * FROWS;
            const __half2* up = &s_u[r * US + cc + 1];
            __half2 u00 = up[0],      u01 = up[1],      u02 = up[2];
            __half2 u10 = up[US],                       u12 = up[US+2];
            __half2 u20 = up[2*US],   u21 = up[2*US+1], u22 = up[2*US+2];
            // column sums (1,2,1 vertical) -> d/dx ; row sums -> d/dy, packed
            __half2 l0 = __hadd2(u00, u20); l0 = __hfma2(two, u10, l0);
            __half2 l2 = __hadd2(u02, u22); l2 = __hfma2(two, u12, l2);
            __half2 dxv = __hmul2(__hsub2(l2, l0), eighth);   // (dudx, dvdx)
            __half2 t0h = __hadd2(u00, u02); t0h = __hfma2(two, u01, t0h);
            __half2 t2h = __hadd2(u20, u22); t2h = __hfma2(two, u21, t2h);
            __half2 dyv = __hmul2(__hsub2(t2h, t0h), eighth); // (dudy, dvdy)
            float2 fx = __half22float2(dxv);
            float2 fy = __half22float2(dyv);
            float cv = __builtin_amdgcn_sqrtf(
                fmaf(fx.x, fx.x, fmaf(fx.y, fx.y,
                fmaf(fy.x, fy.x, fy.y * fy.y))) + EPSF);
            if (!FAST) {
                int gfr = f0 + r - 2, gtc = t0 + cc - 2;
                if (!(((unsigned)gfr < (unsigned)F_DIM) &
                      ((unsigned)gtc < (unsigned)T_DIM))) cv = 0.f;
            }
            ((__half*)s_P2)[2 * (r * FS + cc) + 1] = __float2half_rn(cv);
        }
        // D1 merged into this slot: j0 vertical (trace,diff): P0 -> tmp
        // (C touches s_u/s_P2.y; D1 touches s_P0/s_tmp — independent)
        vpass_pair(s_P0, (__half2*)s_tmp);
        __syncthreads();
    };

    for (int c = 0; c < C_DIM; ++c) {
        if (c) __syncthreads();   // protect s_x/s_tmp overwrite (c==1 only)

        // ---- Phase A: pure ds_writes from prefetched regs ----
        st_tile(pf);
        __syncthreads();
        if (c == 0) ld_tile(xp1, pf);   // issue next channel's loads NOW

        if (interior) phaseBCD1(BoolC<true>{});
        else          phaseBCD1(BoolC<false>{});

        // ====== Phase D: separable jobs; job k horiz fused with job k+1 vert ======
        float trace_s[4], diff_s[4];
        __half2* tmp_h2 = (__half2*)s_tmp;

        // D2: j0 horizontal (f32 accumulate, entropy core) ; j1 vertical: P1 -> P0
        #pragma unroll
        for (int s = 0; s < 4; ++s) {
            int ry = ty + 8 * s;
            float a = 0.f, bv = 0.f;
            #pragma unroll
            for (int j = 0; j < 5; ++j) {
                float2 v = __half22float2(tmp_h2[ry * FS + tx + j]);
                a += w[j] * v.x; bv += w[j] * v.y;
            }
            trace_s[s] = a; diff_s[s] = bv;
        }
        vpass_pair(s_P1, s_P0);
        __syncthreads();

        // D3: j1 horizontal (vxy,tp) + entropy/temporal ; j2 vertical: P2 -> tmp
        #pragma unroll
        for (int s = 0; s < 4; ++s) {
            int ry = ty + 8 * s;
            __half2 a = h2z;
            #pragma unroll
            for (int j = 0; j < 5; ++j)
                a = __hfma2(wh2[j], s_P0[ry * FS + tx + j], a);
            float2 v = __half22float2(a);          // (vxy_s, tp)
            float trace = trace_s[s], diff = diff_s[s];
            float disc  = __builtin_amdgcn_sqrtf(
                              fmaxf(diff * diff + 4.f * v.x * v.x, 0.f) + EPSF);
            float l1 = fmaxf(0.5f * (trace + disc), EPSF);
            float l2 = fmaxf(0.5f * (trace - disc), EPSF);
            float inv = __builtin_amdgcn_rcpf(l1 + l2 + EPSF);
            float p1 = l1 * inv, p2 = l2 * inv;
            // v_log_f32 IS log2 — matches reference's ln(p)/ln(2)
            float ent = -(p1 * __builtin_amdgcn_logf(p1 + EPSF)
                        + p2 * __builtin_amdgcn_logf(p2 + EPSF));
            acc[0][s] += 0.5f * clamp01(ent);
            acc[4][s] += 0.5f * clamp01(v.y);
        }
        vpass_pair(s_P2, tmp_h2);
        __syncthreads();

        // D4: j2 horizontal (sp,cvs) ; j3 vertical: u -> P1 (paired uint2)
        #pragma unroll
        for (int s = 0; s < 4; ++s) {
            int ry = ty + 8 * s;
            __half2 a = h2z;
            #pragma unroll
            for (int j = 0; j < 5; ++j)
                a = __hfma2(wh2[j], tmp_h2[ry * FS + tx + j], a);
            float2 v = __half22float2(a);          // (sp, cvs)
            acc[5][s] += 0.5f * clamp01(v.x);
            acc[2][s] += 0.5f * v.y;
        }
        {
            // u(r+i+1, cc+1), cc = 2p,2p+1 -> word (r+i+1)*US + 2 + 2p: aligned
            const uint2* su2 = (const uint2*)s_u;
            uint2* dP1 = (uint2*)s_P1;
            for (int idx = tid; idx < TILE * FH2; idx += 256) {
                int r = idx / FH2, p = idx - r * FH2;
                const uint2* sp = su2 + (r + 1) * (US/2) + 1 + p;
                __half2 a0 = h2z, a1 = h2z;
                #pragma unroll
                for (int i = 0; i < 5; ++i) {
                    uint2 v = sp[i * (US/2)];
                    a0 = __hfma2(wh2[i], *(const __half2*)&v.x, a0);
                    a1 = __hfma2(wh2[i], *(const __half2*)&v.y, a1);
                }
                uint2 o; o.x = *(const unsigned*)&a0; o.y = *(const unsigned*)&a1;
                dP1[idx] = o;
            }
        }
        __syncthreads();

        // D5: j3 horizontal (alignment) ; j4 vertical: x^2 -> tmp (paired float2)
        #pragma unroll
        for (int s = 0; s < 4; ++s) {
            int ry = ty + 8 * s;
            __half2 a = h2z;
            #pragma unroll
            for (int j = 0; j < 5; ++j)
                a = __hfma2(wh2[j], s_P1[ry * FS + tx + j], a);
            float2 v = __half22float2(a);          // (ua, va)
            acc[1][s] += 0.5f * clamp01(
                __builtin_amdgcn_sqrtf(v.x * v.x + v.y * v.y + EPSF));
        }
        {
            // x(r+i+2, cc+2), cc = 2p,2p+1 -> word (r+i+2)*XS + 2 + 2p: aligned
            const float2* sx2 = (const float2*)s_x;
            float2* dt2 = (float2*)s_tmp;
            for (int idx = tid; idx < TILE * FH2; idx += 256) {
                int r = idx / FH2, p = idx - r * FH2;
                const float2* sp = sx2 + (r + 2) * (XS/2) + 1 + p;
                float a = 0.f, bv = 0.f;
                #pragma unroll
                for (int i = 0; i < 5; ++i) {
                    float2 v = sp[i * (XS/2)];
                    a  = fmaf(w[i], v.x * v.x, a);
                    bv = fmaf(w[i], v.y * v.y, bv);
                }
                dt2[idx] = make_float2(a, bv);
            }
        }
        __syncthreads();

        // D6: j4 horizontal (le) + harmonic epilogue (no barrier after)
        #pragma unroll
        for (int s = 0; s < 4; ++s) {
            int ry = ty + 8 * s;
            float le = 0.f;
            #pragma unroll
            for (int j = 0; j < 5; ++j)
                le += w[j] * s_tmp[ry * FS + tx + j];
            float xm  = s_x[(ry + 1) * XS + tx + 4];
            float x0v = s_x[(ry + 4) * XS + tx + 4];
            float xpv = s_x[(ry + 7) * XS + tx + 4];
            float harm = fabsf(2.f * x0v - xm - xpv);
            acc[3][s] += 0.5f * clamp01(harm * __builtin_amdgcn_rcpf(le + EPSF));
        }
    }

    // ---- write 6 output planes, coalesced ----
    const size_t plane = (size_t)B_DIM * F_DIM * T_DIM;
    const size_t base  = (size_t)b * F_DIM * T_DIM + (size_t)f0 * T_DIM + t0 + tx;
    #pragma unroll
    for (int k = 0; k < 6; ++k)
        #pragma unroll
        for (int s = 0; s < 4; ++s)
            out[k * plane + base + (size_t)(ty + 8 * s) * T_DIM] = acc[k][s];
}

extern "C" void kernel_launch(void* const* d_in, const int* in_sizes, int n_in,
                              void* d_out, int out_size, void* d_ws, size_t ws_size,
                              hipStream_t stream) {
    const float* x  = (const float*)d_in[0];
    const float* gk = (const float*)d_in[1];
    float* out = (float*)d_out;
    dim3 grid(T_DIM / TILE, F_DIM / TILE, B_DIM);   // 64 x 8 x 8 = 4096 blocks
    dim3 block(32, 8);                              // 256 threads = 4 waves
    audio_struct_fused<<<grid, block, 0, stream>>>(x, gk, out);
}

// Round 5
// 221.611 us; speedup vs baseline: 1.1945x; 1.1945x over previous
//
#include <hip/hip_runtime.h>
#include <hip/hip_fp16.h>

// AudioStructuralAnalyzer fused kernel, round 7.
// vs round 6 (ABORTED at load/launch): removed the amdgpu_waves_per_eu
// attribute — the only new element vs the passing round-5 build — and
// restored the proven __launch_bounds__(256, 4).
// vs round 4 (127 us, passing): keeps exactly two changes, both present
// and functionally validated in round 5's passing run:
//  - Phase C and D1 merged into one barrier slot (C: reads s_u, writes
//    P2.y; D1: reads P0, writes tmp — independent buffers)
//  - loop-top barrier only for c==1
//  => 15 barriers/block instead of 18.
// Arithmetic bit-identical to round 4 (absmax stays 0.00390625).

#define F_DIM 256
#define T_DIM 2048
#define B_DIM 8
#define C_DIM 2
#define TILE  32

#define XROWS 40          // x tile: halo 4
#define XS    40          // even stride (float2 loads stay aligned)
#define UROWS 38          // (ux,uy): halo 3
#define US    40          // stored with +1 col shift: u(r,cc) at word r*US+cc+1
#define FROWS 36          // field tiles: halo 2
#define FS    36
#define FH2   18          // FS/2 uint2 pairs per row
#define EPSF  1e-10f

template<bool V> struct BoolC { static constexpr bool value = V; };

static __device__ __forceinline__ __half2 pack_h2(float a, float b) {
    auto v = __builtin_amdgcn_cvt_pkrtz(a, b);   // v_cvt_pkrtz_f16_f32, 1 inst
    return *(__half2*)&v;
}
static __device__ __forceinline__ float clamp01(float x) {
    return fminf(fmaxf(x, 0.f), 1.f);
}

__global__ __launch_bounds__(256, 4)
void audio_struct_fused(const float* __restrict__ x_in,
                        const float* __restrict__ gk_in,
                        float* __restrict__ out)
{
    __shared__ __align__(16) float   s_x [XROWS*XS];    // 6400 B
    __shared__ __align__(16) __half2 s_u [UROWS*US];    // 6080 B (ux,uy), col-shifted
    __shared__ __align__(16) __half2 s_P0[FROWS*FS];    // 5184 B (trace,diff)
    __shared__ __align__(16) __half2 s_P1[FROWS*FS];    // 5184 B (sxy,tin) -> (ua,va)
    __shared__ __align__(16) __half2 s_P2[FROWS*FS];    // 5184 B (sf,cv)
    __shared__ __align__(16) float   s_tmp[TILE*FS];    // 4608 B ping-pong
    // total 32640 B -> 5 blocks/CU (160 KiB)

    const int tx  = threadIdx.x;          // 0..31 (time)
    const int ty  = threadIdx.y;          // 0..7  (freq)
    const int tid = ty * 32 + tx;
    const int t0  = blockIdx.x * TILE;
    const int f0  = blockIdx.y * TILE;
    const int b   = blockIdx.z;

    // 1D gaussian = normalized middle row of the separable 5x5 kernel
    float r0 = gk_in[10], r1 = gk_in[11], r2 = gk_in[12], r3 = gk_in[13], r4 = gk_in[14];
    float winv = __builtin_amdgcn_rcpf(r0 + r1 + r2 + r3 + r4);
    const float w[5] = {r0*winv, r1*winv, r2*winv, r3*winv, r4*winv};
    const __half2 wh2[5] = {pack_h2(w[0],w[0]), pack_h2(w[1],w[1]), pack_h2(w[2],w[2]),
                            pack_h2(w[3],w[3]), pack_h2(w[4],w[4])};
    const __half2 h2z    = pack_h2(0.f, 0.f);
    const __half2 two    = pack_h2(2.f, 2.f);
    const __half2 eighth = pack_h2(0.125f, 0.125f);

    // paired pk vertical pass: dst[idx] = sum_i w[i]*src[idx + i*FH2] (uint2 lanes)
    auto vpass_pair = [&](const __half2* src, __half2* dst) {
        const uint2* s = (const uint2*)src;
        uint2* d = (uint2*)dst;
        for (int idx = tid; idx < TILE * FH2; idx += 256) {
            __half2 a0 = h2z, a1 = h2z;
            #pragma unroll
            for (int i = 0; i < 5; ++i) {
                uint2 v = s[idx + i * FH2];
                a0 = __hfma2(wh2[i], *(const __half2*)&v.x, a0);
                a1 = __hfma2(wh2[i], *(const __half2*)&v.y, a1);
            }
            uint2 o; o.x = *(const unsigned*)&a0; o.y = *(const unsigned*)&a1;
            d[idx] = o;
        }
    };

    float acc[6][4];
    #pragma unroll
    for (int k = 0; k < 6; ++k)
        #pragma unroll
        for (int s = 0; s < 4; ++s) acc[k][s] = 0.0f;

    const bool interior = (f0 >= 4) && (f0 + TILE + 4 <= F_DIM) &&
                          (t0 >= 4) && (t0 + TILE + 4 <= T_DIM);

    // ---- Phases A, B, C(+D1) templated on interior fast path ----
    auto phaseABCD1 = [&](const float* xp, auto FASTC) {
        constexpr bool FAST = decltype(FASTC)::value;

        // ---- Phase A: load x tile + halo 4 (float2, never straddles edges) ----
        for (int idx = tid; idx < XROWS * 20; idx += 256) {
            int r  = idx / 20, c2 = idx - r * 20;
            float2 v;
            if (FAST) {
                v = *(const float2*)(xp + (size_t)(f0 + r - 4) * T_DIM + (t0 + c2 * 2 - 4));
            } else {
                int gf = f0 + r - 4;
                int gt = t0 + c2 * 2 - 4;
                v = make_float2(0.f, 0.f);
                if ((unsigned)gf < (unsigned)F_DIM && (unsigned)gt < (unsigned)T_DIM)
                    v = *(const float2*)(xp + (size_t)gf * T_DIM + gt);
            }
            *(float2*)&s_x[r * XS + c2 * 2] = v;
        }
        __syncthreads();

        // ---- Phase B: (ux,uy) on 38x38; packed fields on 36x36 ----
        for (int idx = tid; idx < UROWS * UROWS; idx += 256) {
            int r = idx / UROWS, cc = idx - r * UROWS;
            float ux = 0.f, uy = 0.f, trp = 0.f, dfp = 0.f, sxy = 0.f,
                  tin = 0.f, sf = 0.f;
            bool ok = true;
            if (!FAST) {
                int gfr = f0 + r - 3, gtc = t0 + cc - 3;
                ok = ((unsigned)gfr < (unsigned)F_DIM) & ((unsigned)gtc < (unsigned)T_DIM);
            }
            if (ok) {
                const float* xc = &s_x[(r + 1) * XS + (cc + 1)];
                float x00 = xc[-XS-1], x01 = xc[-XS], x02 = xc[-XS+1];
                float x10 = xc[-1],                   x12 = xc[1];
                float x20 = xc[XS-1],  x21 = xc[XS],  x22 = xc[XS+1];
                // cross-correlation (XLA conv does not flip kernels)
                float gfv = ((x20 + 2.f*x21 + x22) - (x00 + 2.f*x01 + x02)) * 0.125f;
                float gtv = ((x02 + 2.f*x12 + x22) - (x00 + 2.f*x10 + x20)) * 0.125f;
                float gte = gtv + EPSF;
                float g2f = gfv * gfv;
                float d2  = fmaf(gte, gte, g2f);
                float rh  = __builtin_amdgcn_rsqf(d2);
                ux = gte * rh;                  // cos(atan2(gf, gt+eps))
                uy = gfv * rh;                  // sin(atan2(gf, gt+eps))
                // m2 = |grad|^2 + eps = mag^2;  vx=mag*ux, vy=mag*uy =>
                // trp = vx^2+vy^2 = m2,  dfp = vx^2-vy^2 = m2(ux-uy)(ux+uy),
                // sxy = vx*vy = m2*ux*uy  (identical algebra, no sqrt needed)
                float m2 = fmaf(gtv, gtv, g2f) + EPSF;
                trp = m2;
                dfp = m2 * (ux - uy) * (ux + uy);
                sxy = m2 * ux * uy;
                tin = __builtin_amdgcn_rcpf(1.0f + fabsf(gtv));
                sf  = fabsf(gfv);
            }
            s_u[r * US + cc + 1] = pack_h2(ux, uy);   // +1 col shift
            if (r >= 1 && r < UROWS - 1 && cc >= 1 && cc < UROWS - 1) {
                int fi = (r - 1) * FS + (cc - 1);
                s_P0[fi] = pack_h2(trp, dfp);
                s_P1[fi] = pack_h2(sxy, tin);
                s_P2[fi] = pack_h2(sf, 0.f);   // .y = cv, filled in Phase C
            }
        }
        __syncthreads();

        // ---- Phase C: curv on 36x36, packed-h2 sobel over (ux,uy) ----
        for (int idx = tid; idx < FROWS * FROWS; idx += 256) {
            int r = idx / FROWS, cc = idx - r * FROWS;
            const __half2* up = &s_u[r * US + cc + 1];
            __half2 u00 = up[0],      u01 = up[1],      u02 = up[2];
            __half2 u10 = up[US],                       u12 = up[US+2];
            __half2 u20 = up[2*US],   u21 = up[2*US+1], u22 = up[2*US+2];
            // column sums (1,2,1 vertical) -> d/dx ; row sums -> d/dy, packed
            __half2 l0 = __hadd2(u00, u20); l0 = __hfma2(two, u10, l0);
            __half2 l2 = __hadd2(u02, u22); l2 = __hfma2(two, u12, l2);
            __half2 dxv = __hmul2(__hsub2(l2, l0), eighth);   // (dudx, dvdx)
            __half2 t0h = __hadd2(u00, u02); t0h = __hfma2(two, u01, t0h);
            __half2 t2h = __hadd2(u20, u22); t2h = __hfma2(two, u21, t2h);
            __half2 dyv = __hmul2(__hsub2(t2h, t0h), eighth); // (dudy, dvdy)
            float2 fx = __half22float2(dxv);
            float2 fy = __half22float2(dyv);
            float cv = __builtin_amdgcn_sqrtf(
                fmaf(fx.x, fx.x, fmaf(fx.y, fx.y,
                fmaf(fy.x, fy.x, fy.y * fy.y))) + EPSF);
            if (!FAST) {
                int gfr = f0 + r - 2, gtc = t0 + cc - 2;
                if (!(((unsigned)gfr < (unsigned)F_DIM) &
                      ((unsigned)gtc < (unsigned)T_DIM))) cv = 0.f;
            }
            ((__half*)s_P2)[2 * (r * FS + cc) + 1] = __float2half_rn(cv);
        }
        // D1 merged into this slot: j0 vertical (trace,diff): P0 -> tmp
        // (C touches s_u/s_P2.y; D1 touches s_P0/s_tmp — independent)
        vpass_pair(s_P0, (__half2*)s_tmp);
        __syncthreads();
    };

    for (int c = 0; c < C_DIM; ++c) {
        if (c) __syncthreads();   // protect LDS reuse (c==1 only)

        const float* xp = x_in + (size_t)(b * C_DIM + c) * F_DIM * T_DIM;
        if (interior) phaseABCD1(xp, BoolC<true>{});
        else          phaseABCD1(xp, BoolC<false>{});

        // ====== Phase D: separable jobs; job k horiz fused with job k+1 vert ======
        float trace_s[4], diff_s[4];
        __half2* tmp_h2 = (__half2*)s_tmp;

        // D2: j0 horizontal (f32 accumulate, entropy core) ; j1 vertical: P1 -> P0
        #pragma unroll
        for (int s = 0; s < 4; ++s) {
            int ry = ty + 8 * s;
            float a = 0.f, bv = 0.f;
            #pragma unroll
            for (int j = 0; j < 5; ++j) {
                float2 v = __half22float2(tmp_h2[ry * FS + tx + j]);
                a += w[j] * v.x; bv += w[j] * v.y;
            }
            trace_s[s] = a; diff_s[s] = bv;
        }
        vpass_pair(s_P1, s_P0);
        __syncthreads();

        // D3: j1 horizontal (vxy,tp) + entropy/temporal ; j2 vertical: P2 -> tmp
        #pragma unroll
        for (int s = 0; s < 4; ++s) {
            int ry = ty + 8 * s;
            __half2 a = h2z;
            #pragma unroll
            for (int j = 0; j < 5; ++j)
                a = __hfma2(wh2[j], s_P0[ry * FS + tx + j], a);
            float2 v = __half22float2(a);          // (vxy_s, tp)
            float trace = trace_s[s], diff = diff_s[s];
            float disc  = __builtin_amdgcn_sqrtf(
                              fmaxf(diff * diff + 4.f * v.x * v.x, 0.f) + EPSF);
            float l1 = fmaxf(0.5f * (trace + disc), EPSF);
            float l2 = fmaxf(0.5f * (trace - disc), EPSF);
            float inv = __builtin_amdgcn_rcpf(l1 + l2 + EPSF);
            float p1 = l1 * inv, p2 = l2 * inv;
            // v_log_f32 IS log2 — matches reference's ln(p)/ln(2)
            float ent = -(p1 * __builtin_amdgcn_logf(p1 + EPSF)
                        + p2 * __builtin_amdgcn_logf(p2 + EPSF));
            acc[0][s] += 0.5f * clamp01(ent);
            acc[4][s] += 0.5f * clamp01(v.y);
        }
        vpass_pair(s_P2, tmp_h2);
        __syncthreads();

        // D4: j2 horizontal (sp,cvs) ; j3 vertical: u -> P1 (paired uint2)
        #pragma unroll
        for (int s = 0; s < 4; ++s) {
            int ry = ty + 8 * s;
            __half2 a = h2z;
            #pragma unroll
            for (int j = 0; j < 5; ++j)
                a = __hfma2(wh2[j], tmp_h2[ry * FS + tx + j], a);
            float2 v = __half22float2(a);          // (sp, cvs)
            acc[5][s] += 0.5f * clamp01(v.x);
            acc[2][s] += 0.5f * v.y;
        }
        {
            // u(r+i+1, cc+1), cc = 2p,2p+1 -> word (r+i+1)*US + 2 + 2p: aligned
            const uint2* su2 = (const uint2*)s_u;
            uint2* dP1 = (uint2*)s_P1;
            for (int idx = tid; idx < TILE * FH2; idx += 256) {
                int r = idx / FH2, p = idx - r * FH2;
                const uint2* sp = su2 + (r + 1) * (US/2) + 1 + p;
                __half2 a0 = h2z, a1 = h2z;
                #pragma unroll
                for (int i = 0; i < 5; ++i) {
                    uint2 v = sp[i * (US/2)];
                    a0 = __hfma2(wh2[i], *(const __half2*)&v.x, a0);
                    a1 = __hfma2(wh2[i], *(const __half2*)&v.y, a1);
                }
                uint2 o; o.x = *(const unsigned*)&a0; o.y = *(const unsigned*)&a1;
                dP1[idx] = o;
            }
        }
        __syncthreads();

        // D5: j3 horizontal (alignment) ; j4 vertical: x^2 -> tmp (paired float2)
        #pragma unroll
        for (int s = 0; s < 4; ++s) {
            int ry = ty + 8 * s;
            __half2 a = h2z;
            #pragma unroll
            for (int j = 0; j < 5; ++j)
                a = __hfma2(wh2[j], s_P1[ry * FS + tx + j], a);
            float2 v = __half22float2(a);          // (ua, va)
            acc[1][s] += 0.5f * clamp01(
                __builtin_amdgcn_sqrtf(v.x * v.x + v.y * v.y + EPSF));
        }
        {
            // x(r+i+2, cc+2), cc = 2p,2p+1 -> word (r+i+2)*XS + 2 + 2p: aligned
            const float2* sx2 = (const float2*)s_x;
            float2* dt2 = (float2*)s_tmp;
            for (int idx = tid; idx < TILE * FH2; idx += 256) {
                int r = idx / FH2, p = idx - r * FH2;
                const float2* sp = sx2 + (r + 2) * (XS/2) + 1 + p;
                float a = 0.f, bv = 0.f;
                #pragma unroll
                for (int i = 0; i < 5; ++i) {
                    float2 v = sp[i * (XS/2)];
                    a  = fmaf(w[i], v.x * v.x, a);
                    bv = fmaf(w[i], v.y * v.y, bv);
                }
                dt2[idx] = make_float2(a, bv);
            }
        }
        __syncthreads();

        // D6: j4 horizontal (le) + harmonic epilogue (no trailing barrier)
        #pragma unroll
        for (int s = 0; s < 4; ++s) {
            int ry = ty + 8 * s;
            float le = 0.f;
            #pragma unroll
            for (int j = 0; j < 5; ++j)
                le += w[j] * s_tmp[ry * FS + tx + j];
            float xm  = s_x[(ry + 1) * XS + tx + 4];
            float x0v = s_x[(ry + 4) * XS + tx + 4];
            float xpv = s_x[(ry + 7) * XS + tx + 4];
            float harm = fabsf(2.f * x0v - xm - xpv);
            acc[3][s] += 0.5f * clamp01(harm * __builtin_amdgcn_rcpf(le + EPSF));
        }
    }

    // ---- write 6 output planes, coalesced ----
    const size_t plane = (size_t)B_DIM * F_DIM * T_DIM;
    const size_t base  = (size_t)b * F_DIM * T_DIM + (size_t)f0 * T_DIM + t0 + tx;
    #pragma unroll
    for (int k = 0; k < 6; ++k)
        #pragma unroll
        for (int s = 0; s < 4; ++s)
            out[k * plane + base + (size_t)(ty + 8 * s) * T_DIM] = acc[k][s];
}

extern "C" void kernel_launch(void* const* d_in, const int* in_sizes, int n_in,
                              void* d_out, int out_size, void* d_ws, size_t ws_size,
                              hipStream_t stream) {
    const float* x  = (const float*)d_in[0];
    const float* gk = (const float*)d_in[1];
    float* out = (float*)d_out;
    dim3 grid(T_DIM / TILE, F_DIM / TILE, B_DIM);   // 64 x 8 x 8 = 4096 blocks
    dim3 block(32, 8);                              // 256 threads = 4 waves
    audio_struct_fused<<<grid, block, 0, stream>>>(x, gk, out);
}